// Round 4
// baseline (142.392 us; speedup 1.0000x reference)
//
#include <hip/hip_runtime.h>
#include <hip/hip_bf16.h>
#include <stdint.h>
#include <stddef.h>

// Problem constants
#define NIMG 32
#define C_IN 128
#define C_OUT 256
#define HW 56
#define SP 3136            // 56*56
#define STOT (NIMG * SP)   // 100352
#define PD 58              // padded spatial dim
#define KTOT 1152          // 128*9

// GEMM tiling
#define BM 256
#define BN 224             // 448 tiles = 8*56 (XCD-exact)
#define NTILES (STOT / BN) // 448
#define NKT (KTOT / 64)    // 18 K-tiles, 36 phases (slices) of K=32
#define THREADS 512
#define GRID 256           // persistent: block does tiles bid, bid+256

typedef __attribute__((ext_vector_type(8))) short bf16x8;
typedef __attribute__((ext_vector_type(4))) float f32x4;

__device__ __forceinline__ void gload16(const void* g, void* l) {
    __builtin_amdgcn_global_load_lds(
        (const __attribute__((address_space(1))) void*)g,
        (__attribute__((address_space(3))) void*)l,
        16, 0, 0);
}

#define BAR() do { asm volatile("" ::: "memory"); \
                   __builtin_amdgcn_s_barrier();  \
                   asm volatile("" ::: "memory"); } while (0)
#define LGKM(n) do { asm volatile("s_waitcnt lgkmcnt(" #n ")" ::: "memory"); \
                     __builtin_amdgcn_sched_barrier(0); } while (0)
#define VMCNT(n) do { asm volatile("s_waitcnt vmcnt(" #n ")" ::: "memory"); \
                      __builtin_amdgcn_sched_barrier(0); } while (0)

__device__ __forceinline__ unsigned short bf2u(float f) {
    __hip_bfloat16 b = __float2bfloat16(f);
    return *reinterpret_cast<unsigned short*>(&b);
}

// ---------------------------------------------------------------------------
// Prepass 1: NCHW fp32 -> padded NHWC bf16 [n][58][58][128], borders zeroed
// inline. HBM-floor bound (~12.5 us: 51 MB read + 27.5 MB write).
// ---------------------------------------------------------------------------
__global__ __launch_bounds__(256)
void pad_transpose_kernel(const float* __restrict__ x,
                          __hip_bfloat16* __restrict__ xp) {
    __shared__ float t[C_IN][HW + 1];
    const int hp = blockIdx.x % PD;
    const int n  = blockIdx.x / PD;
    const int h  = hp - 1;
    const bool interior = ((unsigned)h < (unsigned)HW);
    if (interior) {
        for (int idx = threadIdx.x; idx < C_IN * HW; idx += 256) {
            int ci = idx / HW, w = idx - ci * HW;
            t[ci][w] = x[((size_t)n * C_IN + ci) * SP + h * HW + w];
        }
    }
    __syncthreads();
    ushort4* dst = (ushort4*)(xp + ((size_t)n * PD + hp) * PD * C_IN);
    for (int idx = threadIdx.x; idx < PD * C_IN / 4; idx += 256) {
        int el = idx * 4;
        int wp = el >> 7, c0 = el & 127;
        ushort4 v = {0, 0, 0, 0};
        if (interior && wp >= 1 && wp <= HW) {
            int w = wp - 1;
            v.x = bf2u(t[c0 + 0][w]);
            v.y = bf2u(t[c0 + 1][w]);
            v.z = bf2u(t[c0 + 2][w]);
            v.w = bf2u(t[c0 + 3][w]);
        }
        dst[idx] = v;
    }
}

// ---------------------------------------------------------------------------
// Prepass 2: weight OIHW fp32 -> [tap][co][ci] bf16, tap = kh*3+kw
// ---------------------------------------------------------------------------
__global__ void wt_transform_kernel(const float* __restrict__ wgt,
                                    __hip_bfloat16* __restrict__ wt) {
    int idx = blockIdx.x * 256 + threadIdx.x;     // 294912 exact
    int ci  = idx & 127;
    int co  = (idx >> 7) & 255;
    int tap = idx >> 15;
    wt[idx] = __float2bfloat16(wgt[(co * C_IN + ci) * 9 + tap]);
}

// ---------------------------------------------------------------------------
// Main: implicit GEMM, 256x224 tile, 8 waves (4M x 2N, 64x112 each).
// A (weights) loaded DIRECT global->VGPR one phase ahead (L2-resident,
// line-aligned); only B goes through LDS: ring of 4 regions x 16 KB.
// 36 K-slices (K=32 each). Phase p (per wave):
//   BAR; RD_B(frags p+1 <- region (p+1)&3); LDA(A-frags p+1);
//   STG_B(slice p+3 -> region (p+3)&3); VMCNT(#issued); LGKM(7); 28 MFMA.
// Stage->read distance 2 phases; VMCNT(n)=this-phase-issues drains all
// prior vmem (A p-1 consumed now, stage p-2 landed before its read).
// Persistent: 256 blocks, tiles bid and bid+256.
// ---------------------------------------------------------------------------
__global__ __launch_bounds__(THREADS, 2)
void conv_mfma_kernel(const __hip_bfloat16* __restrict__ xp,
                      const __hip_bfloat16* __restrict__ wt,
                      const float* __restrict__ bias,
                      float* __restrict__ out) {
    extern __shared__ short smem[];   // 4 regions * 8192 shorts = 64 KiB

    const int tid  = threadIdx.x;
    const int lane = tid & 63;
    const int wid  = tid >> 6;
    const int rl   = lane & 15;
    const int kq   = lane >> 4;                 // k-quarter 0..3
    const int wm   = (wid >> 1) * 64;           // 4 M-waves
    const int wn   = (wid & 1) * 112;           // 2 N-waves

    // B LDS read offset (swizzled; row*32 shorts = 64B rows)
    const int rch = ((kq ^ ((lane >> 1) & 3)) << 3);
    const int bRd = (wn + rl) * 32 + rch;
    // B staging (inverse-swizzled global source, rule #21)
    const int cg_el = (((lane & 3) ^ ((lane >> 3) & 3)) << 3);
    const int srow  = wid * 16 + (lane >> 2);   // 0..127
    const int ldsw  = wid * 512;
    // A direct-load lane base: row = wm+rl (+mi*16), k-quarter kq
    const __hip_bfloat16* Abase = wt + (wm + rl) * C_IN + kq * 8;

    // bias preload (tile-invariant)
    float bv[4][4];
    #pragma unroll
    for (int mi = 0; mi < 4; ++mi)
        #pragma unroll
        for (int j = 0; j < 4; ++j)
            bv[mi][j] = bias[wm + mi * 16 + (kq << 2) + j];

    for (int tile = blockIdx.x; tile < NTILES; tile += GRID) {
        const int wg = (tile & 7) * 56 + (tile >> 3);   // XCD-bijective
        const int s0 = wg * BN;

        int s_r = s0 + srow;
        int n_  = s_r / SP, rem = s_r - n_ * SP;
        int h_  = rem / HW, w_ = rem - h_ * HW;
        const int bS0 = ((n_ * PD + h_) * PD + w_) * C_IN + cg_el;
        int srow2 = 128 + srow; if (srow2 > BN - 1) srow2 = BN - 1;
        s_r = s0 + srow2;
        n_ = s_r / SP; rem = s_r - n_ * SP; h_ = rem / HW; w_ = rem - h_ * HW;
        const int bS1 = ((n_ * PD + h_) * PD + w_) * C_IN + cg_el;

        auto STG = [&](int s, int r) {      // stage B slice s into region r
            int tap = s >> 2, ci0 = (s & 3) << 5;
            int kh = (tap * 11) >> 5, kw = tap - kh * 3;
            const __hip_bfloat16* src = xp + (kh * PD + kw) * C_IN + ci0;
            short* d = smem + r * 8192 + ldsw;
            gload16(src + bS0, d);
            gload16(src + bS1, d + 4096);
        };
        auto LDA = [&](bf16x8* ga, int s) { // A-frags direct from global
            const __hip_bfloat16* src = Abase + ((s >> 2) << 15) + ((s & 3) << 5);
            #pragma unroll
            for (int mi = 0; mi < 4; ++mi)
                ga[mi] = *(const bf16x8*)(src + mi * 16 * C_IN);
        };
        auto RD = [&](bf16x8* fb, int r) {  // B-frags from LDS
            const short* Bb = smem + r * 8192;
            #pragma unroll
            for (int j = 0; j < 7; ++j)
                fb[j] = *(const bf16x8*)(Bb + bRd + j * 512);
        };

        f32x4 acc[4][7] = {};
        bf16x8 ga0[4], ga1[4], fb0[7], fb1[7];

        #define MM(GA, FB) do { \
            __builtin_amdgcn_s_setprio(1); \
            _Pragma("unroll") \
            for (int mi = 0; mi < 4; ++mi) \
                _Pragma("unroll") \
                for (int ni = 0; ni < 7; ++ni) \
                    acc[mi][ni] = __builtin_amdgcn_mfma_f32_16x16x32_bf16( \
                        GA[mi], FB[ni], acc[mi][ni], 0, 0, 0); \
            __builtin_amdgcn_s_setprio(0); \
        } while (0)

        // ---- prologue ----
        LDA(ga0, 0);                          // 4 vm
        STG(0, 0); STG(1, 1); STG(2, 2);      // 6 vm
        VMCNT(2);    // drains ga0 + slice0 + slice1 (slice2 in flight)
        BAR();
        RD(fb0, 0);                           // 7 lgkm

        for (int t = 0; t < NKT; ++t) {
            const int rb = (t & 1) << 1;

            // ---- phase A (p = 2t): MM slice 2t ----
            BAR();
            RD(fb1, rb + 1);
            LDA(ga1, 2 * t + 1);
            if (t <= 16) { STG(2 * t + 3, (rb + 3) & 3); VMCNT(6); }
            else          { VMCNT(4); }
            LGKM(7);
            MM(ga0, fb0);

            // ---- phase B (p = 2t+1): MM slice 2t+1 ----
            BAR();
            if (t <= 16) {
                RD(fb0, (rb + 2) & 3);
                LDA(ga0, 2 * t + 2);
                if (t <= 15) { STG(2 * t + 4, rb); VMCNT(6); }
                else          { VMCNT(4); }
                LGKM(7);
            } else {
                VMCNT(0); LGKM(0);
            }
            MM(ga1, fb1);
        }
        #undef MM

        // ---- epilogue: D col = spatial (lane&15), row = co ----
        #pragma unroll
        for (int ni = 0; ni < 7; ++ni) {
            int s  = s0 + wn + ni * 16 + rl;
            int n  = s / SP;
            int si = s - n * SP;
            float* obase = out + (size_t)n * C_OUT * SP + si;
            #pragma unroll
            for (int mi = 0; mi < 4; ++mi) {
                int cob = wm + mi * 16 + (kq << 2);
                #pragma unroll
                for (int j = 0; j < 4; ++j) {
                    obase[(size_t)(cob + j) * SP] = acc[mi][ni][j] + bv[mi][j];
                }
            }
        }
    }
}

// ---------------------------------------------------------------------------
// Fallback: direct fp32 conv (only if ws too small). Slow but correct.
// ---------------------------------------------------------------------------
__global__ void conv_direct_kernel(const float* __restrict__ x,
                                   const float* __restrict__ wgt,
                                   const float* __restrict__ bias,
                                   float* __restrict__ out) {
    long idx = (long)blockIdx.x * 256 + threadIdx.x;
    if (idx >= (long)NIMG * C_OUT * SP) return;
    int si = (int)(idx % SP);
    int co = (int)((idx / SP) % C_OUT);
    int n  = (int)(idx / ((long)SP * C_OUT));
    int h = si / HW, w = si - (si / HW) * HW;
    float acc = bias[co];
    for (int ci = 0; ci < C_IN; ++ci) {
        const float* xr = x + ((size_t)n * C_IN + ci) * SP;
        const float* wr = wgt + ((size_t)co * C_IN + ci) * 9;
        #pragma unroll
        for (int kh = 0; kh < 3; ++kh) {
            int ih = h + kh - 1;
            if (ih < 0 || ih >= HW) continue;
            #pragma unroll
            for (int kw = 0; kw < 3; ++kw) {
                int iw = w + kw - 1;
                if (iw < 0 || iw >= HW) continue;
                acc += xr[ih * HW + iw] * wr[kh * 3 + kw];
            }
        }
    }
    out[idx] = acc;
}

// ---------------------------------------------------------------------------
extern "C" void kernel_launch(void* const* d_in, const int* in_sizes, int n_in,
                              void* d_out, int out_size, void* d_ws, size_t ws_size,
                              hipStream_t stream) {
    const float* x    = (const float*)d_in[0];
    const float* wgt  = (const float*)d_in[1];
    const float* bias = (const float*)d_in[2];
    float* out = (float*)d_out;

    const size_t xp_bytes = (size_t)NIMG * PD * PD * C_IN * sizeof(__hip_bfloat16);
    const size_t wt_bytes = (size_t)9 * C_OUT * C_IN * sizeof(__hip_bfloat16);

    if (ws_size >= xp_bytes + wt_bytes) {
        __hip_bfloat16* xp  = (__hip_bfloat16*)d_ws;
        __hip_bfloat16* wtb = (__hip_bfloat16*)((char*)d_ws + xp_bytes);

        pad_transpose_kernel<<<NIMG * PD, 256, 0, stream>>>(x, xp);
        wt_transform_kernel<<<(9 * C_OUT * C_IN) / 256, 256, 0, stream>>>(wgt, wtb);

        hipFuncSetAttribute((const void*)conv_mfma_kernel,
                            hipFuncAttributeMaxDynamicSharedMemorySize, 65536);
        conv_mfma_kernel<<<GRID, THREADS, 65536, stream>>>(xp, wtb, bias, out);
    } else {
        long total = (long)NIMG * C_OUT * SP;
        conv_direct_kernel<<<(int)((total + 255) / 256), 256, 0, stream>>>(
            x, wgt, bias, out);
    }
}

// Round 5
// 106.065 us; speedup vs baseline: 1.3425x; 1.3425x over previous
//
#include <hip/hip_runtime.h>
#include <hip/hip_bf16.h>
#include <stdint.h>
#include <stddef.h>

// Problem constants
#define NIMG 32
#define C_IN 128
#define C_OUT 256
#define HW 56
#define SP 3136            // 56*56
#define STOT (NIMG * SP)   // 100352
#define PD 58              // padded spatial dim
#define KTOT 1152          // 128*9

// GEMM tiling
#define BM 256
#define BN 224             // 448 tiles = 8*56 (XCD-exact)
#define NTILES (STOT / BN) // 448
#define NSLICE 36          // K-slices of 32
#define THREADS 512
#define GRID 224           // persistent: block does tiles bid, bid+224

typedef __attribute__((ext_vector_type(8))) short bf16x8;
typedef __attribute__((ext_vector_type(4))) float f32x4;

__device__ __forceinline__ void gload16(const void* g, void* l) {
    __builtin_amdgcn_global_load_lds(
        (const __attribute__((address_space(1))) void*)g,
        (__attribute__((address_space(3))) void*)l,
        16, 0, 0);
}

#define BAR() do { asm volatile("" ::: "memory"); \
                   __builtin_amdgcn_s_barrier();  \
                   asm volatile("" ::: "memory"); } while (0)
#define LGKM(n) do { asm volatile("s_waitcnt lgkmcnt(" #n ")" ::: "memory"); \
                     __builtin_amdgcn_sched_barrier(0); } while (0)
#define VMCNT(n) do { asm volatile("s_waitcnt vmcnt(" #n ")" ::: "memory"); \
                      __builtin_amdgcn_sched_barrier(0); } while (0)

__device__ __forceinline__ unsigned short bf2u(float f) {
    __hip_bfloat16 b = __float2bfloat16(f);
    return *reinterpret_cast<unsigned short*>(&b);
}

// ---------------------------------------------------------------------------
// Prepass (merged): blocks [0, NIMG*PD) pad+transpose x -> padded NHWC bf16
// [n][58][58][128] with zeroed borders; blocks [NIMG*PD, +1152) transform
// weights OIHW fp32 -> [tap][co][ci] bf16.
// ---------------------------------------------------------------------------
#define PAD_BLOCKS (NIMG * PD)          // 1856
#define WT_BLOCKS  ((9 * C_OUT * C_IN) / 256)  // 1152

__global__ __launch_bounds__(256)
void prep_kernel(const float* __restrict__ x, const float* __restrict__ wgt,
                 __hip_bfloat16* __restrict__ xp, __hip_bfloat16* __restrict__ wt) {
    __shared__ float t[C_IN][HW + 1];
    const int b = blockIdx.x;
    if (b < PAD_BLOCKS) {
        const int hp = b % PD;
        const int n  = b / PD;
        const int h  = hp - 1;
        const bool interior = ((unsigned)h < (unsigned)HW);
        if (interior) {
            for (int idx = threadIdx.x; idx < C_IN * HW; idx += 256) {
                int ci = idx / HW, w = idx - ci * HW;
                t[ci][w] = x[((size_t)n * C_IN + ci) * SP + h * HW + w];
            }
        }
        __syncthreads();
        ushort4* dst = (ushort4*)(xp + ((size_t)n * PD + hp) * PD * C_IN);
        for (int idx = threadIdx.x; idx < PD * C_IN / 4; idx += 256) {
            int el = idx * 4;
            int wp = el >> 7, c0 = el & 127;
            ushort4 v = {0, 0, 0, 0};
            if (interior && wp >= 1 && wp <= HW) {
                int w = wp - 1;
                v.x = bf2u(t[c0 + 0][w]);
                v.y = bf2u(t[c0 + 1][w]);
                v.z = bf2u(t[c0 + 2][w]);
                v.w = bf2u(t[c0 + 3][w]);
            }
            dst[idx] = v;
        }
    } else {
        int idx = (b - PAD_BLOCKS) * 256 + threadIdx.x;   // 294912 exact
        int ci  = idx & 127;
        int co  = (idx >> 7) & 255;
        int tap = idx >> 15;
        wt[idx] = __float2bfloat16(wgt[(co * C_IN + ci) * 9 + tap]);
    }
}

// ---------------------------------------------------------------------------
// Main: implicit GEMM, 256x224 tile, 8 waves (4M x 2N, 64x112 each), A+B
// through LDS ring of 4 regions x 32 KB (A 16KB + B 16KB each), K-slices of
// 32, 36 phases/tile.  Uniform phase p:
//   VMCNT(4); BAR; RD(frags p+1 <- region (p+1)&3); STG(slice p+3 ->
//   region (p+3)&3); LGKM(11); 28 MFMA on frags(p).
// Every phase issues exactly 4 vmem -> VMCNT(4) drains precisely the
// distance-2 stage that filled the region RD is about to read.
// Persistent (GRID=224, 2 tiles/block): tile-1's 3 tail stage slots carry
// the NEXT tile's slices 0-2, so the ring cadence never breaks; tile-2 has
// zero warmup.  Last tile: VMCNT(0) at p=34, no RD at p=35.  Post-epilogue
// VMCNT(0) fences output stores out of the counted-wait domain.
// ---------------------------------------------------------------------------
__global__ __launch_bounds__(THREADS, 2)
void conv_mfma_kernel(const __hip_bfloat16* __restrict__ xp,
                      const __hip_bfloat16* __restrict__ wt,
                      const float* __restrict__ bias,
                      float* __restrict__ out) {
    extern __shared__ short smem[];   // 4 regions * 16384 shorts = 128 KiB

    const int tid  = threadIdx.x;
    const int lane = tid & 63;
    const int wid  = tid >> 6;
    const int rl   = lane & 15;
    const int kq   = lane >> 4;

    // ---- staging constants (inverse-swizzled global source, rule #21) ----
    const int cg_el = (((lane & 3) ^ ((lane >> 3) & 3)) << 3);
    const int srow  = wid * 16 + (lane >> 2);        // 0..127
    const int aS0   = srow * C_IN + cg_el;           // A rows 0-127
    const int aS1   = aS0 + 128 * C_IN;              // A rows 128-255
    const int ldsw  = wid * 512;                     // wave-uniform LDS dest

    // ---- compute-phase read offsets (swizzled) ----
    const int rch = ((kq ^ ((lane >> 1) & 3)) << 3);
    const int wm  = (wid >> 1) * 64;    // 4 M-waves
    const int wn  = (wid & 1) * 112;    // 2 N-waves
    const int aRd = (wm + rl) * 32 + rch;
    const int bRd = (wn + rl) * 32 + rch;

    // ---- per-block tile pair: spatial bases and B staging offsets ----
    int ts0[2], tB0[2], tB1[2];
    #pragma unroll
    for (int it = 0; it < 2; ++it) {
        int tile = blockIdx.x + it * GRID;
        int wg   = (tile & 7) * 56 + (tile >> 3);    // XCD-bijective (448=8*56)
        int s0   = wg * BN;
        ts0[it]  = s0;
        int s_r = s0 + srow;
        int n_  = s_r / SP, rem = s_r - n_ * SP;
        int h_  = rem / HW, w_ = rem - h_ * HW;
        tB0[it] = ((n_ * PD + h_) * PD + w_) * C_IN + cg_el;
        int srow2 = 128 + srow; if (srow2 > BN - 1) srow2 = BN - 1;   // dummy
        s_r = s0 + srow2;
        n_ = s_r / SP; rem = s_r - n_ * SP; h_ = rem / HW; w_ = rem - h_ * HW;
        tB1[it] = ((n_ * PD + h_) * PD + w_) * C_IN + cg_el;
    }

    auto STGx = [&](int sa, int r, int b0, int b1) {
        int tap = sa >> 2, ci0 = (sa & 3) << 5;
        const __hip_bfloat16* wsrc = wt + tap * (C_OUT * C_IN) + ci0;
        short* Ad = smem + r * 16384 + ldsw;
        gload16(wsrc + aS0, Ad);
        gload16(wsrc + aS1, Ad + 4096);
        int kh = (tap * 11) >> 5, kw = tap - kh * 3;
        const __hip_bfloat16* xsrc = xp + (kh * PD + kw) * C_IN + ci0;
        short* Bd = smem + r * 16384 + 8192 + ldsw;
        gload16(xsrc + b0, Bd);
        gload16(xsrc + b1, Bd + 4096);
    };
    auto RD = [&](bf16x8* fa, bf16x8* fb, int r) {
        const short* Ab = smem + r * 16384;
        const short* Bb = Ab + 8192;
        #pragma unroll
        for (int j = 0; j < 4; ++j) fa[j] = *(const bf16x8*)(Ab + aRd + j * 512);
        #pragma unroll
        for (int j = 0; j < 7; ++j) fb[j] = *(const bf16x8*)(Bb + bRd + j * 512);
    };

    // bias preload (tile-invariant)
    float bv[4][4];
    #pragma unroll
    for (int mi = 0; mi < 4; ++mi)
        #pragma unroll
        for (int j = 0; j < 4; ++j)
            bv[mi][j] = bias[wm + mi * 16 + (kq << 2) + j];

    bf16x8 fa0[4], fb0[7], fa1[4], fb1[7];

    #define MM(FA, FB) do { \
        __builtin_amdgcn_s_setprio(1); \
        _Pragma("unroll") \
        for (int mi = 0; mi < 4; ++mi) \
            _Pragma("unroll") \
            for (int ni = 0; ni < 7; ++ni) \
                acc[mi][ni] = __builtin_amdgcn_mfma_f32_16x16x32_bf16( \
                    FA[mi], FB[ni], acc[mi][ni], 0, 0, 0); \
        __builtin_amdgcn_s_setprio(0); \
    } while (0)

    // ---- prologue: tile-0 slices 0,1,2 into regions 0,1,2 ----
    STGx(0, 0, tB0[0], tB1[0]);
    STGx(1, 1, tB0[0], tB1[0]);
    STGx(2, 2, tB0[0], tB1[0]);
    VMCNT(4);     // slices 0,1 landed (slice 2 in flight)
    BAR();
    RD(fa0, fb0, 0);

    #pragma unroll
    for (int it = 0; it < 2; ++it) {
        const bool last = (it == 1);
        const int cB0 = tB0[it], cB1 = tB1[it];
        const int nB0 = tB0[it ^ 1], nB1 = tB1[it ^ 1];   // unused when last

        f32x4 acc[4][7] = {};

        #pragma unroll 1
        for (int t = 0; t < 18; ++t) {
            // ---- even phase p = 2t: MM slice 2t ----
            if (last && t == 17) { VMCNT(0); } else { VMCNT(4); }
            BAR();
            RD(fa1, fb1, (2 * t + 1) & 3);
            {
                int s = 2 * t + 3;
                if (!last || s <= 35) {
                    bool nx = s >= NSLICE;
                    STGx(nx ? s - NSLICE : s, s & 3,
                         nx ? nB0 : cB0, nx ? nB1 : cB1);
                }
            }
            LGKM(11);
            MM(fa0, fb0);

            // ---- odd phase p = 2t+1: MM slice 2t+1 ----
            VMCNT(4);
            BAR();
            const bool doRD = !(last && t == 17);
            if (doRD) {
                RD(fa0, fb0, (2 * t + 2) & 3);
                int s = 2 * t + 4;
                if (!last || s <= 35) {
                    bool nx = s >= NSLICE;
                    STGx(nx ? s - NSLICE : s, s & 3,
                         nx ? nB0 : cB0, nx ? nB1 : cB1);
                }
                LGKM(11);
            } else {
                VMCNT(0); LGKM(0);
            }
            MM(fa1, fb1);
        }

        // ---- epilogue: D col = spatial (lane&15), row = co ----
        const int s0 = ts0[it];
        #pragma unroll
        for (int ni = 0; ni < 7; ++ni) {
            int s  = s0 + wn + ni * 16 + rl;
            int n  = s / SP;
            int si = s - n * SP;
            float* obase = out + (size_t)n * C_OUT * SP + si;
            #pragma unroll
            for (int mi = 0; mi < 4; ++mi) {
                int cob = wm + mi * 16 + (kq << 2);
                #pragma unroll
                for (int j = 0; j < 4; ++j) {
                    obase[(size_t)(cob + j) * SP] = acc[mi][ni][j] + bv[mi][j];
                }
            }
        }
        if (!last) { VMCNT(0); }   // fence stores out of counted-wait domain
    }
    #undef MM
}

// ---------------------------------------------------------------------------
// Fallback: direct fp32 conv (only if ws too small). Slow but correct.
// ---------------------------------------------------------------------------
__global__ void conv_direct_kernel(const float* __restrict__ x,
                                   const float* __restrict__ wgt,
                                   const float* __restrict__ bias,
                                   float* __restrict__ out) {
    long idx = (long)blockIdx.x * 256 + threadIdx.x;
    if (idx >= (long)NIMG * C_OUT * SP) return;
    int si = (int)(idx % SP);
    int co = (int)((idx / SP) % C_OUT);
    int n  = (int)(idx / ((long)SP * C_OUT));
    int h = si / HW, w = si - (si / HW) * HW;
    float acc = bias[co];
    for (int ci = 0; ci < C_IN; ++ci) {
        const float* xr = x + ((size_t)n * C_IN + ci) * SP;
        const float* wr = wgt + ((size_t)co * C_IN + ci) * 9;
        #pragma unroll
        for (int kh = 0; kh < 3; ++kh) {
            int ih = h + kh - 1;
            if (ih < 0 || ih >= HW) continue;
            #pragma unroll
            for (int kw = 0; kw < 3; ++kw) {
                int iw = w + kw - 1;
                if (iw < 0 || iw >= HW) continue;
                acc += xr[ih * HW + iw] * wr[kh * 3 + kw];
            }
        }
    }
    out[idx] = acc;
}

// ---------------------------------------------------------------------------
extern "C" void kernel_launch(void* const* d_in, const int* in_sizes, int n_in,
                              void* d_out, int out_size, void* d_ws, size_t ws_size,
                              hipStream_t stream) {
    const float* x    = (const float*)d_in[0];
    const float* wgt  = (const float*)d_in[1];
    const float* bias = (const float*)d_in[2];
    float* out = (float*)d_out;

    const size_t xp_bytes = (size_t)NIMG * PD * PD * C_IN * sizeof(__hip_bfloat16);
    const size_t wt_bytes = (size_t)9 * C_OUT * C_IN * sizeof(__hip_bfloat16);

    if (ws_size >= xp_bytes + wt_bytes) {
        __hip_bfloat16* xp  = (__hip_bfloat16*)d_ws;
        __hip_bfloat16* wtb = (__hip_bfloat16*)((char*)d_ws + xp_bytes);

        prep_kernel<<<PAD_BLOCKS + WT_BLOCKS, 256, 0, stream>>>(x, wgt, xp, wtb);

        hipFuncSetAttribute((const void*)conv_mfma_kernel,
                            hipFuncAttributeMaxDynamicSharedMemorySize, 131072);
        conv_mfma_kernel<<<GRID, THREADS, 131072, stream>>>(xp, wtb, bias, out);
    } else {
        long total = (long)NIMG * C_OUT * SP;
        conv_direct_kernel<<<(int)((total + 255) / 256), 256, 0, stream>>>(
            x, wgt, bias, out);
    }
}

// Round 6
// 84.920 us; speedup vs baseline: 1.6768x; 1.2490x over previous
//
#include <hip/hip_runtime.h>
#include <hip/hip_bf16.h>
#include <stdint.h>
#include <stddef.h>

// Problem constants
#define NIMG 32
#define C_IN 128
#define C_OUT 256
#define HW 56
#define SP 3136            // 56*56
#define STOT (NIMG * SP)   // 100352
#define PD 58              // padded spatial dim
#define KTOT 1152          // 128*9

// GEMM tiling
#define BM 256
#define BN 224             // 448 tiles = 8*56 (XCD-exact)
#define NSLICE 36          // K-slices of 32
#define THREADS 512

typedef __attribute__((ext_vector_type(8))) short bf16x8;
typedef __attribute__((ext_vector_type(4))) float f32x4;

__device__ __forceinline__ void gload16(const void* g, void* l) {
    __builtin_amdgcn_global_load_lds(
        (const __attribute__((address_space(1))) void*)g,
        (__attribute__((address_space(3))) void*)l,
        16, 0, 0);
}

// Memory-clobber only: orders all memory ops (ds_read/gload_lds) across the
// wait, but leaves register-only MFMAs free for the scheduler (m141 lesson:
// sched_barrier(0) order-pinning costs ~40%).
#define BAR() do { asm volatile("" ::: "memory"); \
                   __builtin_amdgcn_s_barrier();  \
                   asm volatile("" ::: "memory"); } while (0)
#define VMCNT(n) asm volatile("s_waitcnt vmcnt(" #n ")" ::: "memory")

__device__ __forceinline__ unsigned short bf2u(float f) {
    __hip_bfloat16 b = __float2bfloat16(f);
    return *reinterpret_cast<unsigned short*>(&b);
}

// ---------------------------------------------------------------------------
// Prepass (merged): blocks [0, NIMG*PD) pad+transpose x -> padded NHWC bf16
// [n][58][58][128] with zeroed borders; blocks [NIMG*PD, +1152) transform
// weights OIHW fp32 -> [tap][co][ci] bf16.  HBM-floor bound (~13 us).
// ---------------------------------------------------------------------------
#define PAD_BLOCKS (NIMG * PD)                 // 1856
#define WT_BLOCKS  ((9 * C_OUT * C_IN) / 256)  // 1152

__global__ __launch_bounds__(256)
void prep_kernel(const float* __restrict__ x, const float* __restrict__ wgt,
                 __hip_bfloat16* __restrict__ xp, __hip_bfloat16* __restrict__ wt) {
    __shared__ float t[C_IN][HW + 1];
    const int b = blockIdx.x;
    if (b < PAD_BLOCKS) {
        const int hp = b % PD;
        const int n  = b / PD;
        const int h  = hp - 1;
        const bool interior = ((unsigned)h < (unsigned)HW);
        if (interior) {
            for (int idx = threadIdx.x; idx < C_IN * HW; idx += 256) {
                int ci = idx / HW, w = idx - ci * HW;
                t[ci][w] = x[((size_t)n * C_IN + ci) * SP + h * HW + w];
            }
        }
        __syncthreads();
        ushort4* dst = (ushort4*)(xp + ((size_t)n * PD + hp) * PD * C_IN);
        for (int idx = threadIdx.x; idx < PD * C_IN / 4; idx += 256) {
            int el = idx * 4;
            int wp = el >> 7, c0 = el & 127;
            ushort4 v = {0, 0, 0, 0};
            if (interior && wp >= 1 && wp <= HW) {
                int w = wp - 1;
                v.x = bf2u(t[c0 + 0][w]);
                v.y = bf2u(t[c0 + 1][w]);
                v.z = bf2u(t[c0 + 2][w]);
                v.w = bf2u(t[c0 + 3][w]);
            }
            dst[idx] = v;
        }
    } else {
        int idx = (b - PAD_BLOCKS) * 256 + threadIdx.x;   // 294912 exact
        int ci  = idx & 127;
        int co  = (idx >> 7) & 255;
        int tap = idx >> 15;
        wt[idx] = __float2bfloat16(wgt[(co * C_IN + ci) * 9 + tap]);
    }
}

// ---------------------------------------------------------------------------
// Main: implicit GEMM, 256x224 tile, 8 waves (4M x 2N, 64x112 each), A+B via
// LDS ring of 4 regions x 32 KB.  36 K-slices of 32.  Phase p:
//   VMCNT(4); BAR; RD(frags p+1 <- region (p+1)&3); STG(slice p+3); MM(p)
// Staging distance 3, in-flight 2 slices (8 loads); VMCNT(4) drains slice
// p+1 exactly (in-order vmem retirement).  Tail: phase 34 uses VMCNT(0)
// (slice 35 is the only outstanding stage - VMCNT(4) would not drain it).
// No lgkm pins: compiler inserts fine-grained lgkmcnt and interleaves the
// ds_reads into the MFMA stream.
// ---------------------------------------------------------------------------
__global__ __launch_bounds__(THREADS, 2)
void conv_mfma_kernel(const __hip_bfloat16* __restrict__ xp,
                      const __hip_bfloat16* __restrict__ wt,
                      const float* __restrict__ bias,
                      float* __restrict__ out) {
    extern __shared__ short smem[];   // 4 regions * 16384 shorts = 128 KiB

    const int tid  = threadIdx.x;
    const int lane = tid & 63;
    const int wid  = tid >> 6;
    const int rl   = lane & 15;
    const int kq   = lane >> 4;
    const int wg   = (blockIdx.x & 7) * 56 + (blockIdx.x >> 3);  // XCD-bijective
    const int s0   = wg * BN;

    // ---- staging constants (inverse-swizzled global source, rule #21) ----
    const int cg_el = (((lane & 3) ^ ((lane >> 3) & 3)) << 3);
    const int srow  = wid * 16 + (lane >> 2);        // 0..127
    const int aS0   = srow * C_IN + cg_el;           // A rows 0-127
    const int aS1   = aS0 + 128 * C_IN;              // A rows 128-255
    const int ldsw  = wid * 512;                     // wave-uniform LDS dest
    int s_r = s0 + srow;
    int n_  = s_r / SP, rem = s_r - n_ * SP;
    int h_  = rem / HW, w_ = rem - h_ * HW;
    const int bS0 = ((n_ * PD + h_) * PD + w_) * C_IN + cg_el;
    int srow2 = 128 + srow; if (srow2 > BN - 1) srow2 = BN - 1;   // dummy
    s_r = s0 + srow2;
    n_ = s_r / SP; rem = s_r - n_ * SP; h_ = rem / HW; w_ = rem - h_ * HW;
    const int bS1 = ((n_ * PD + h_) * PD + w_) * C_IN + cg_el;

    // ---- compute-phase read offsets (swizzled) ----
    const int rch = ((kq ^ ((lane >> 1) & 3)) << 3);
    const int wm  = (wid >> 1) * 64;    // 4 M-waves
    const int wn  = (wid & 1) * 112;    // 2 N-waves
    const int aRd = (wm + rl) * 32 + rch;
    const int bRd = (wn + rl) * 32 + rch;

    auto STG = [&](int s) {            // stage slice s into region s&3
        int tap = s >> 2, ci0 = (s & 3) << 5;
        const __hip_bfloat16* wsrc = wt + tap * (C_OUT * C_IN) + ci0;
        short* Ad = smem + (s & 3) * 16384 + ldsw;
        gload16(wsrc + aS0, Ad);
        gload16(wsrc + aS1, Ad + 4096);
        int kh = (tap * 11) >> 5, kw = tap - kh * 3;
        const __hip_bfloat16* xsrc = xp + (kh * PD + kw) * C_IN + ci0;
        short* Bd = smem + (s & 3) * 16384 + 8192 + ldsw;
        gload16(xsrc + bS0, Bd);
        gload16(xsrc + bS1, Bd + 4096);
    };
    auto RD = [&](bf16x8* fa, bf16x8* fb, int r) {
        const short* Ab = smem + r * 16384;
        const short* Bb = Ab + 8192;
        #pragma unroll
        for (int j = 0; j < 4; ++j) fa[j] = *(const bf16x8*)(Ab + aRd + j * 512);
        #pragma unroll
        for (int j = 0; j < 7; ++j) fb[j] = *(const bf16x8*)(Bb + bRd + j * 512);
    };

    // bias preload (tile-invariant)
    float bv[4][4];
    #pragma unroll
    for (int mi = 0; mi < 4; ++mi)
        #pragma unroll
        for (int j = 0; j < 4; ++j)
            bv[mi][j] = bias[wm + mi * 16 + (kq << 2) + j];

    f32x4 acc[4][7] = {};
    bf16x8 fa0[4], fb0[7], fa1[4], fb1[7];

    #define MM(FA, FB) do { \
        __builtin_amdgcn_s_setprio(1); \
        _Pragma("unroll") \
        for (int mi = 0; mi < 4; ++mi) \
            _Pragma("unroll") \
            for (int ni = 0; ni < 7; ++ni) \
                acc[mi][ni] = __builtin_amdgcn_mfma_f32_16x16x32_bf16( \
                    FA[mi], FB[ni], acc[mi][ni], 0, 0, 0); \
        __builtin_amdgcn_s_setprio(0); \
    } while (0)

    // ---- prologue: slices 0,1,2 staged; VMCNT(8) -> slice 0 landed ----
    STG(0); STG(1); STG(2);
    VMCNT(8);
    BAR();
    RD(fa0, fb0, 0);

    for (int t = 0; t < 18; ++t) {
        // ---- even phase p = 2t: MM slice 2t; read slice 2t+1 ----
        if (t == 17) { VMCNT(0); } else { VMCNT(4); }
        BAR();
        RD(fa1, fb1, (2 * t + 1) & 3);
        if (t <= 16) STG(2 * t + 3);
        MM(fa0, fb0);

        // ---- odd phase p = 2t+1: MM slice 2t+1; read slice 2t+2 ----
        if (t < 17) {
            VMCNT(4);
            BAR();
            RD(fa0, fb0, (2 * t + 2) & 3);
            if (t <= 15) STG(2 * t + 4);
            MM(fa1, fb1);
        } else {
            BAR();
            MM(fa1, fb1);
        }
    }
    #undef MM

    // ---- epilogue: D col = spatial (lane&15), row = co ----
    #pragma unroll
    for (int ni = 0; ni < 7; ++ni) {
        int s  = s0 + wn + ni * 16 + rl;
        int n  = s / SP;
        int si = s - n * SP;
        float* obase = out + (size_t)n * C_OUT * SP + si;
        #pragma unroll
        for (int mi = 0; mi < 4; ++mi) {
            int cob = wm + mi * 16 + (kq << 2);
            #pragma unroll
            for (int j = 0; j < 4; ++j) {
                obase[(size_t)(cob + j) * SP] = acc[mi][ni][j] + bv[mi][j];
            }
        }
    }
}

// ---------------------------------------------------------------------------
// Fallback: direct fp32 conv (only if ws too small). Slow but correct.
// ---------------------------------------------------------------------------
__global__ void conv_direct_kernel(const float* __restrict__ x,
                                   const float* __restrict__ wgt,
                                   const float* __restrict__ bias,
                                   float* __restrict__ out) {
    long idx = (long)blockIdx.x * 256 + threadIdx.x;
    if (idx >= (long)NIMG * C_OUT * SP) return;
    int si = (int)(idx % SP);
    int co = (int)((idx / SP) % C_OUT);
    int n  = (int)(idx / ((long)SP * C_OUT));
    int h = si / HW, w = si - (si / HW) * HW;
    float acc = bias[co];
    for (int ci = 0; ci < C_IN; ++ci) {
        const float* xr = x + ((size_t)n * C_IN + ci) * SP;
        const float* wr = wgt + ((size_t)co * C_IN + ci) * 9;
        #pragma unroll
        for (int kh = 0; kh < 3; ++kh) {
            int ih = h + kh - 1;
            if (ih < 0 || ih >= HW) continue;
            #pragma unroll
            for (int kw = 0; kw < 3; ++kw) {
                int iw = w + kw - 1;
                if (iw < 0 || iw >= HW) continue;
                acc += xr[ih * HW + iw] * wr[kh * 3 + kw];
            }
        }
    }
    out[idx] = acc;
}

// ---------------------------------------------------------------------------
extern "C" void kernel_launch(void* const* d_in, const int* in_sizes, int n_in,
                              void* d_out, int out_size, void* d_ws, size_t ws_size,
                              hipStream_t stream) {
    const float* x    = (const float*)d_in[0];
    const float* wgt  = (const float*)d_in[1];
    const float* bias = (const float*)d_in[2];
    float* out = (float*)d_out;

    const size_t xp_bytes = (size_t)NIMG * PD * PD * C_IN * sizeof(__hip_bfloat16);
    const size_t wt_bytes = (size_t)9 * C_OUT * C_IN * sizeof(__hip_bfloat16);

    if (ws_size >= xp_bytes + wt_bytes) {
        __hip_bfloat16* xp  = (__hip_bfloat16*)d_ws;
        __hip_bfloat16* wtb = (__hip_bfloat16*)((char*)d_ws + xp_bytes);

        prep_kernel<<<PAD_BLOCKS + WT_BLOCKS, 256, 0, stream>>>(x, wgt, xp, wtb);

        hipFuncSetAttribute((const void*)conv_mfma_kernel,
                            hipFuncAttributeMaxDynamicSharedMemorySize, 131072);
        conv_mfma_kernel<<<STOT / BN, THREADS, 131072, stream>>>(xp, wtb, bias, out);
    } else {
        long total = (long)NIMG * C_OUT * SP;
        conv_direct_kernel<<<(int)((total + 255) / 256), 256, 0, stream>>>(
            x, wgt, bias, out);
    }
}